// Round 10
// baseline (58.777 us; speedup 1.0000x reference)
//
#include <hip/hip_runtime.h>

#define BATCH 4096
#define SEQ   80
#define EMBED 100
#define UNITS 64
#define NTILE (BATCH / 16)      // 256 batch tiles of 16 rows
#define NTASK (SEQ * NTILE)     // 20480 (t, tile) proj tasks
#define PTASK 5                 // tasks per proj wave (16 t-segments)

typedef float f32x4  __attribute__((ext_vector_type(4)));
typedef short bf16x8 __attribute__((ext_vector_type(8)));

#define MFMA16 __builtin_amdgcn_mfma_f32_16x16x32_bf16

// ---- ws layout (bytes) ----
#define XW_OFF  0u           // uint2[NTASK*4*64] = 41,943,040 B (bf16 D-frags)
#define EMB_OFF 41943040u    // ushort[10000*128] = 2,560,000 B
#define W1T_OFF 44503040u    // ushort[64*128]
#define U1T_OFF 44519424u    // ushort[64*64]
#define W2T_OFF 44527616u
#define U2T_OFF 44535808u    // end = 44,544,000 B

__device__ __forceinline__ unsigned f2bfu(float f) {
    union { float f; unsigned u; } x; x.f = f;
    return (x.u + 0x7fffu + ((x.u >> 16) & 1u)) >> 16;   // RNE (prep only)
}
__device__ __forceinline__ unsigned cvtpk(float lo, float hi) {
    unsigned r;
    asm("v_cvt_pk_bf16_f32 %0, %1, %2" : "=v"(r) : "v"(lo), "v"(hi));
    return r;
}
__device__ __forceinline__ float bflo(unsigned u) {
    union { unsigned u; float f; } x; x.u = u << 16; return x.f;
}
__device__ __forceinline__ float bfhi(unsigned u) {
    union { unsigned u; float f; } x; x.u = u & 0xffff0000u; return x.f;
}
// branch-free exact-tails tanh: 1 - 2/(e^{2x}+1)
__device__ __forceinline__ float fast_tanh(float x) {
    float e = __builtin_amdgcn_exp2f(x * 2.8853900817779268f);   // e^{2x}
    float r = __builtin_amdgcn_rcpf(e + 1.0f);
    return __builtin_fmaf(-2.0f, r, 1.0f);
}

// ---------------------------------------------------------------------------
// prep: bf16 tables — emb padded to K=128, transposed W1/U1/W2/U2. (unchanged)
// ---------------------------------------------------------------------------
__global__ __launch_bounds__(256) void prep_kernel(
    const float* __restrict__ emb, const float* __restrict__ W1,
    const float* __restrict__ U1,  const float* __restrict__ W2,
    const float* __restrict__ U2,  char* __restrict__ ws)
{
    ushort* emb_bf = (ushort*)(ws + EMB_OFF);
    ushort* w1t    = (ushort*)(ws + W1T_OFF);
    ushort* u1t    = (ushort*)(ws + U1T_OFF);
    ushort* w2t    = (ushort*)(ws + W2T_OFF);
    ushort* u2t    = (ushort*)(ws + U2T_OFF);
    const int tid    = blockIdx.x * 256 + threadIdx.x;
    const int stride = gridDim.x * 256;

    for (int i = tid; i < 10000 * 16; i += stride) {
        const int r = i >> 4, kc = (i & 15) * 8;
        unsigned w[4];
        #pragma unroll
        for (int p = 0; p < 4; ++p) {
            const int k0 = kc + 2 * p;
            unsigned lo = (k0     < EMBED) ? f2bfu(emb[r * EMBED + k0])     : 0u;
            unsigned hi = (k0 + 1 < EMBED) ? f2bfu(emb[r * EMBED + k0 + 1]) : 0u;
            w[p] = lo | (hi << 16);
        }
        uint4 v; v.x = w[0]; v.y = w[1]; v.z = w[2]; v.w = w[3];
        *(uint4*)(emb_bf + (size_t)r * 128 + kc) = v;
    }
    for (int i = tid; i < UNITS * 128; i += stride) {
        const int u = i >> 7, k = i & 127;
        w1t[i] = (k < EMBED) ? (ushort)f2bfu(W1[k * UNITS + u]) : (ushort)0;
    }
    for (int i = tid; i < UNITS * UNITS; i += stride) {
        const int u = i >> 6, k = i & 63;
        u1t[i] = (ushort)f2bfu(U1[k * UNITS + u]);
        w2t[i] = (ushort)f2bfu(W2[k * UNITS + u]);
        u2t[i] = (ushort)f2bfu(U2[k * UNITS + u]);
    }
}

// ---------------------------------------------------------------------------
// proj v3: 4096 persistent waves (1024 blocks x 4), PTASK=5 tasks each,
// 4 waves/SIMD TLP to hide emb-gather latency. Same math/layout as R9.
// ---------------------------------------------------------------------------
__global__ __launch_bounds__(256) void proj_kernel(
    const int*    __restrict__ tokens,
    const float*  __restrict__ b1,
    const ushort* __restrict__ emb_bf,
    const ushort* __restrict__ w1t,
    uint2*        __restrict__ xw)
{
    const int lane = threadIdx.x & 63;
    const int wid  = threadIdx.x >> 6;
    const int m15  = lane & 15;
    const int kgrp = lane >> 4;
    const int gwid = blockIdx.x * 4 + wid;      // 0..4095
    const int tile = gwid & 255;
    const int t0   = (gwid >> 8) * PTASK;       // 0,5,...,75

    bf16x8 aW1[4][4];
    #pragma unroll
    for (int mt = 0; mt < 4; ++mt)
        #pragma unroll
        for (int ks = 0; ks < 4; ++ks)
            aW1[mt][ks] = *(const bf16x8*)(w1t + (16 * mt + m15) * 128 + kgrp * 8 + 32 * ks);
    f32x4 b1c[4];
    #pragma unroll
    for (int mt = 0; mt < 4; ++mt)
        b1c[mt] = *(const f32x4*)(b1 + 16 * mt + 4 * kgrp);

    const int b = tile * 16 + m15;
    const int* tokp = tokens + (size_t)b * SEQ;

    bf16x8 cur0, cur1, cur2, cur3;
    {
        const int tk = tokp[t0];
        const ushort* er = emb_bf + (size_t)tk * 128 + kgrp * 8;
        cur0 = *(const bf16x8*)(er);      cur1 = *(const bf16x8*)(er + 32);
        cur2 = *(const bf16x8*)(er + 64); cur3 = *(const bf16x8*)(er + 96);
    }
    int tokB = tokp[t0 + 1 < SEQ ? t0 + 1 : SEQ - 1];

    #pragma unroll
    for (int i = 0; i < PTASK; ++i) {
        const int t = t0 + i;
        bf16x8 nxt0, nxt1, nxt2, nxt3;
        {
            const ushort* er = emb_bf + (size_t)tokB * 128 + kgrp * 8;
            nxt0 = *(const bf16x8*)(er);      nxt1 = *(const bf16x8*)(er + 32);
            nxt2 = *(const bf16x8*)(er + 64); nxt3 = *(const bf16x8*)(er + 96);
        }
        {
            const int tn = t + 2;
            tokB = tokp[tn < SEQ ? (tn < t0 + PTASK ? tn : t0 + PTASK - 1) : SEQ - 1];
        }

        f32x4 acc[4];
        #pragma unroll
        for (int mt = 0; mt < 4; ++mt) acc[mt] = b1c[mt];
        #pragma unroll
        for (int mt = 0; mt < 4; ++mt) {
            acc[mt] = MFMA16(aW1[mt][0], cur0, acc[mt], 0, 0, 0);
            acc[mt] = MFMA16(aW1[mt][1], cur1, acc[mt], 0, 0, 0);
            acc[mt] = MFMA16(aW1[mt][2], cur2, acc[mt], 0, 0, 0);
            acc[mt] = MFMA16(aW1[mt][3], cur3, acc[mt], 0, 0, 0);
        }

        const size_t task = (size_t)t * NTILE + tile;
        #pragma unroll
        for (int mt = 0; mt < 4; ++mt) {
            uint2 q;
            q.x = cvtpk(acc[mt][0], acc[mt][1]);
            q.y = cvtpk(acc[mt][2], acc[mt][3]);
            xw[(task * 4 + mt) * 64 + lane] = q;
        }
        cur0 = nxt0; cur1 = nxt1; cur2 = nxt2; cur3 = nxt3;
    }
}

// ---------------------------------------------------------------------------
// rnn v2: layer-split. 8 waves/block, 256 blocks -> 2 waves/SIMD.
// Waves 0-3 (slice s): h2[T] = tanh(b2 + W2 h1[T] + U2 h2[T-1])
// Waves 4-7 (slice s): h1[T+1] = tanh(xw[T+1] + U1 h1[T])  (xw streamed)
// One barrier per phase; per-wave work halved vs R8.
// ---------------------------------------------------------------------------
__global__ __launch_bounds__(512, 1) void rnn_kernel(
    const uint2*  __restrict__ xw,
    const ushort* __restrict__ u1t,
    const ushort* __restrict__ w2t,
    const ushort* __restrict__ u2t,
    const float*  __restrict__ b2,
    const float*  __restrict__ Wo,
    const float*  __restrict__ bo,
    float*        __restrict__ out)
{
    __shared__ __align__(16) char h1L[2][2048];   // [buf][16b x 64u bf16, swz]
    __shared__ __align__(16) char h2L[2][2048];
    __shared__ float headp[4][16];

    const int lane = threadIdx.x & 63;
    const int W    = threadIdx.x >> 6;    // 0..7
    const int isl1 = W >> 2;              // 0: layer2 wave, 1: layer1 wave
    const int s    = W & 3;               // unit-slice
    const int m15  = lane & 15;
    const int kgrp = lane >> 4;
    const int swz  = (m15 & 7) << 4;
    const int wg   = blockIdx.x;

    // zero h2[-1] (buf 0)
    {
        uint4 z = {0u, 0u, 0u, 0u};
        if (threadIdx.x < 128) ((uint4*)h2L[0])[threadIdx.x] = z;
    }

    const int urow  = 16 * s + m15;
    const int ubase = 16 * s + 4 * kgrp;

    // per-role registers
    bf16x8 aU1[2], aW2[2], aU2[2];
    f32x4 b2c = {0.f, 0.f, 0.f, 0.f};
    const size_t TSTRIDE = (size_t)NTILE * 4 * 64;
    const uint2* xwp = xw + ((size_t)wg * 4 + s) * 64 + lane;
    uint2 qA, qB;

    if (isl1) {
        #pragma unroll
        for (int ks = 0; ks < 2; ++ks)
            aU1[ks] = *(const bf16x8*)(u1t + urow * 64 + kgrp * 8 + 32 * ks);
        uint2 q0 = xwp[0];
        qA = xwp[TSTRIDE];
        qB = xwp[2 * TSTRIDE];
        // prologue: h1[0] = tanh(xw[0]) -> buf 0
        float t0 = fast_tanh(bflo(q0.x)), t1 = fast_tanh(bfhi(q0.x));
        float t2 = fast_tanh(bflo(q0.y)), t3 = fast_tanh(bfhi(q0.y));
        uint2 pk; pk.x = cvtpk(t0, t1); pk.y = cvtpk(t2, t3);
        *(uint2*)(h1L[0] + m15 * 128 + ((32 * s + 8 * kgrp) ^ swz)) = pk;
    } else {
        #pragma unroll
        for (int ks = 0; ks < 2; ++ks) {
            aW2[ks] = *(const bf16x8*)(w2t + urow * 64 + kgrp * 8 + 32 * ks);
            aU2[ks] = *(const bf16x8*)(u2t + urow * 64 + kgrp * 8 + 32 * ks);
        }
        b2c = *(const f32x4*)(b2 + ubase);
    }
    asm volatile("s_waitcnt lgkmcnt(0)" ::: "memory");
    __builtin_amdgcn_s_barrier();

    float d2f0 = 0.f, d2f1 = 0.f, d2f2 = 0.f, d2f3 = 0.f;

#define LBAR() do { asm volatile("s_waitcnt lgkmcnt(0)" ::: "memory"); \
                    __builtin_amdgcn_s_barrier(); } while (0)
#define PHASE(T, P, Q)                                                           \
  {                                                                              \
    if (isl1) {                                                                  \
        const int tn = ((T) + 3 < SEQ) ? (T) + 3 : SEQ - 1;                      \
        uint2 qC = xwp[(size_t)tn * TSTRIDE];                                    \
        bf16x8 bh1a = *(const bf16x8*)(h1L[P] + m15 * 128 + ((kgrp * 16     ) ^ swz)); \
        bf16x8 bh1b = *(const bf16x8*)(h1L[P] + m15 * 128 + ((kgrp * 16 + 64) ^ swz)); \
        f32x4 d1 = {bflo(qA.x), bfhi(qA.x), bflo(qA.y), bfhi(qA.y)};             \
        d1 = MFMA16(aU1[0], bh1a, d1, 0, 0, 0);                                  \
        d1 = MFMA16(aU1[1], bh1b, d1, 0, 0, 0);                                  \
        float n0 = fast_tanh(d1[0]);                                             \
        float n1 = fast_tanh(d1[1]);                                             \
        float n2 = fast_tanh(d1[2]);                                             \
        float n3 = fast_tanh(d1[3]);                                             \
        uint2 pk; pk.x = cvtpk(n0, n1); pk.y = cvtpk(n2, n3);                    \
        *(uint2*)(h1L[Q] + m15 * 128 + ((32 * s + 8 * kgrp) ^ swz)) = pk;        \
        qA = qB; qB = qC;                                                        \
    } else {                                                                     \
        bf16x8 bh1a = *(const bf16x8*)(h1L[P] + m15 * 128 + ((kgrp * 16     ) ^ swz)); \
        bf16x8 bh1b = *(const bf16x8*)(h1L[P] + m15 * 128 + ((kgrp * 16 + 64) ^ swz)); \
        bf16x8 bh2a = *(const bf16x8*)(h2L[P] + m15 * 128 + ((kgrp * 16     ) ^ swz)); \
        bf16x8 bh2b = *(const bf16x8*)(h2L[P] + m15 * 128 + ((kgrp * 16 + 64) ^ swz)); \
        f32x4 dC = b2c;                                                          \
        dC = MFMA16(aW2[0], bh1a, dC, 0, 0, 0);                                  \
        dC = MFMA16(aW2[1], bh1b, dC, 0, 0, 0);                                  \
        f32x4 dD = {0.f, 0.f, 0.f, 0.f};                                         \
        dD = MFMA16(aU2[0], bh2a, dD, 0, 0, 0);                                  \
        dD = MFMA16(aU2[1], bh2b, dD, 0, 0, 0);                                  \
        d2f0 = fast_tanh(dC[0] + dD[0]);                                         \
        d2f1 = fast_tanh(dC[1] + dD[1]);                                         \
        d2f2 = fast_tanh(dC[2] + dD[2]);                                         \
        d2f3 = fast_tanh(dC[3] + dD[3]);                                         \
        uint2 pk; pk.x = cvtpk(d2f0, d2f1); pk.y = cvtpk(d2f2, d2f3);            \
        *(uint2*)(h2L[Q] + m15 * 128 + ((32 * s + 8 * kgrp) ^ swz)) = pk;        \
    }                                                                            \
    LBAR();                                                                      \
  }

    for (int t = 0; t < SEQ; t += 2) {
        PHASE(t,     0, 1)
        PHASE(t + 1, 1, 0)
    }
#undef PHASE
#undef LBAR

    // ---- head: out[b] = sigmoid(h2[79] @ Wo + bo); only L2 waves hold d2f ----
    if (!isl1) {
        const f32x4 woc = *(const f32x4*)(Wo + ubase);
        float p = d2f0 * woc[0] + d2f1 * woc[1] + d2f2 * woc[2] + d2f3 * woc[3];
        p += __shfl_xor(p, 16, 64);
        p += __shfl_xor(p, 32, 64);
        if (lane < 16) headp[s][lane] = p;
    }
    __syncthreads();
    if (threadIdx.x < 16) {
        const float z = headp[0][threadIdx.x] + headp[1][threadIdx.x]
                      + headp[2][threadIdx.x] + headp[3][threadIdx.x] + bo[0];
        const float e = __builtin_amdgcn_exp2f(-z * 1.4426950408889634f);
        out[wg * 16 + threadIdx.x] = __builtin_amdgcn_rcpf(1.0f + e);
    }
}

extern "C" void kernel_launch(void* const* d_in, const int* in_sizes, int n_in,
                              void* d_out, int out_size, void* d_ws, size_t ws_size,
                              hipStream_t stream) {
    const int*   tokens = (const int*)  d_in[0];
    const float* emb    = (const float*)d_in[1];
    const float* W1     = (const float*)d_in[2];
    const float* U1     = (const float*)d_in[3];
    const float* b1     = (const float*)d_in[4];
    const float* W2     = (const float*)d_in[5];
    const float* U2     = (const float*)d_in[6];
    const float* b2     = (const float*)d_in[7];
    const float* Wo     = (const float*)d_in[8];
    const float* bo     = (const float*)d_in[9];
    float* out = (float*)d_out;
    char*  ws  = (char*)d_ws;

    prep_kernel<<<640, 256, 0, stream>>>(emb, W1, U1, W2, U2, ws);
    proj_kernel<<<1024, 256, 0, stream>>>(
        tokens, b1,
        (const ushort*)(ws + EMB_OFF), (const ushort*)(ws + W1T_OFF),
        (uint2*)(ws + XW_OFF));
    rnn_kernel<<<NTILE, 512, 0, stream>>>(
        (const uint2*)(ws + XW_OFF),
        (const ushort*)(ws + U1T_OFF), (const ushort*)(ws + W2T_OFF),
        (const ushort*)(ws + U2T_OFF),
        b2, Wo, bo, out);
}